// Round 1
// baseline (899.399 us; speedup 1.0000x reference)
//
#include <hip/hip_runtime.h>

#define MU 5
static constexpr int Hh = 1024, Ww = 1024, Bb = 8;
static constexpr int NPIX = Bb * Hh * Ww;

__device__ __forceinline__ float fast_tanh(float x) {
    // tanh(x) = 1 - 2/(exp(2x)+1)
    float e = __expf(2.0f * x);
    return 1.0f - 2.0f / (e + 1.0f);
}

__global__ void sobel_kernel(const float* __restrict__ in,
                             float2* __restrict__ tang,
                             float* __restrict__ mag,
                             unsigned int* __restrict__ maxbits) {
    int id = blockIdx.x * blockDim.x + threadIdx.x;
    if (id >= NPIX) return;
    int x = id & (Ww - 1);
    int y = (id >> 10) & (Hh - 1);
    int b = id >> 20;
    const float* p = in + (size_t)b * Hh * Ww;

    auto at = [&](int yy, int xx) -> float {
        if (yy < 0 || yy >= Hh || xx < 0 || xx >= Ww) return 0.0f;
        return p[yy * Ww + xx];
    };

    float a00 = at(y - 1, x - 1), a01 = at(y - 1, x), a02 = at(y - 1, x + 1);
    float a10 = at(y,     x - 1),                     a12 = at(y,     x + 1);
    float a20 = at(y + 1, x - 1), a21 = at(y + 1, x), a22 = at(y + 1, x + 1);

    // JAX conv = cross-correlation, no kernel flip.
    float gx = (a02 - a00) + 2.0f * (a12 - a10) + (a22 - a20);
    float gy = (a20 - a00) + 2.0f * (a21 - a01) + (a22 - a02);

    float m = sqrtf(gx * gx + gy * gy);
    mag[id] = m;
    float inv = (m == 0.0f) ? 1.0f : (1.0f / m);
    tang[id] = make_float2(-gy * inv, gx * inv);

    // block max -> atomic
    float v = m;
    #pragma unroll
    for (int off = 32; off; off >>= 1) v = fmaxf(v, __shfl_xor(v, off));
    __shared__ float smax[4];
    int lane = threadIdx.x & 63, wid = threadIdx.x >> 6;
    if (lane == 0) smax[wid] = v;
    __syncthreads();
    if (threadIdx.x == 0) {
        float bm = fmaxf(fmaxf(smax[0], smax[1]), fmaxf(smax[2], smax[3]));
        atomicMax(maxbits, __float_as_uint(bm));
    }
}

template <int DY, int DX, bool NORM, bool FINAL>
__global__ void etf_pass(const float2* __restrict__ src,
                         float2* __restrict__ dstI,
                         float* __restrict__ dstP,
                         const float* __restrict__ mag,
                         const unsigned int* __restrict__ maxbits) {
    int id = blockIdx.x * blockDim.x + threadIdx.x;
    if (id >= NPIX) return;
    float scale = 1.0f / __uint_as_float(*maxbits);
    int x = id & (Ww - 1);
    int y = (id >> 10) & (Hh - 1);
    int b = id >> 20;
    int base = b * (Hh * Ww);

    float2 tX = src[id];
    float mX = mag[id] * scale;
    float accx = 0.0f, accy = 0.0f;

    #pragma unroll
    for (int i = -MU; i <= MU; ++i) {
        int yy = y + i * DY;
        int xx = x + i * DX;
        if (yy < 0 || yy >= Hh || xx < 0 || xx >= Ww) continue;
        int j = base + yy * Ww + xx;
        float2 tY = src[j];
        float mY = mag[j] * scale;
        float d = tX.x * tY.x + tX.y * tY.y;
        float w = (fast_tanh(mY - mX) + 1.0f) * d * 0.5f;
        accx += tY.x * w;
        accy += tY.y * w;
    }

    if (NORM) {
        float n = sqrtf(accx * accx + accy * accy);
        float inv = (n == 0.0f) ? 1.0f : (1.0f / n);
        accx *= inv;
        accy *= inv;
    }

    if (FINAL) {
        dstP[((size_t)(b * 2 + 0) * Hh + y) * Ww + x] = accx;
        dstP[((size_t)(b * 2 + 1) * Hh + y) * Ww + x] = accy;
    } else {
        dstI[id] = make_float2(accx, accy);
    }
}

extern "C" void kernel_launch(void* const* d_in, const int* in_sizes, int n_in,
                              void* d_out, int out_size, void* d_ws, size_t ws_size,
                              hipStream_t stream) {
    const float* in = (const float*)d_in[0];
    float* out = (float*)d_out;
    char* ws = (char*)d_ws;

    float* mag = (float*)ws;                                        // 32 MB
    float2* tA = (float2*)(ws + (size_t)NPIX * sizeof(float));      // 64 MB
    unsigned int* maxb = (unsigned int*)(ws + (size_t)NPIX * sizeof(float)
                                            + (size_t)NPIX * sizeof(float2));
    float2* tOut = (float2*)out;

    hipMemsetAsync(maxb, 0, sizeof(unsigned int), stream);

    const int threads = 256;
    const int blocks = NPIX / threads;

    sobel_kernel<<<blocks, threads, 0, stream>>>(in, tOut, mag, maxb);

    // iteration 1
    etf_pass<1, 0, false, false><<<blocks, threads, 0, stream>>>(tOut, tA, nullptr, mag, maxb);
    etf_pass<0, 1, true,  false><<<blocks, threads, 0, stream>>>(tA, tOut, nullptr, mag, maxb);
    // iteration 2
    etf_pass<1, 0, false, false><<<blocks, threads, 0, stream>>>(tOut, tA, nullptr, mag, maxb);
    etf_pass<0, 1, true,  false><<<blocks, threads, 0, stream>>>(tA, tOut, nullptr, mag, maxb);
    // iteration 3
    etf_pass<1, 0, false, false><<<blocks, threads, 0, stream>>>(tOut, tA, nullptr, mag, maxb);
    etf_pass<0, 1, true,  true ><<<blocks, threads, 0, stream>>>(tA, nullptr, out, mag, maxb);
}

// Round 2
// 560.178 us; speedup vs baseline: 1.6056x; 1.6056x over previous
//
#include <hip/hip_runtime.h>

#define MU 5
static constexpr int Hh = 1024, Ww = 1024, Bb = 8;
static constexpr int NPIX = Bb * Hh * Ww;
static constexpr int SOBEL_THREADS = 256;
static constexpr int SOBEL_BLOCKS = NPIX / SOBEL_THREADS;   // 32768

__device__ __forceinline__ float fast_tanh(float x) {
    // tanh(x) = 1 - 2/(exp(2x)+1)
    float e = __expf(2.0f * x);
    return 1.0f - 2.0f / (e + 1.0f);
}

__global__ void sobel_kernel(const float* __restrict__ in,
                             float2* __restrict__ tang,
                             float* __restrict__ mag,
                             float* __restrict__ partials) {
    int id = blockIdx.x * blockDim.x + threadIdx.x;
    int x = id & (Ww - 1);
    int y = (id >> 10) & (Hh - 1);
    int b = id >> 20;
    const float* p = in + (size_t)b * Hh * Ww;

    auto at = [&](int yy, int xx) -> float {
        if (yy < 0 || yy >= Hh || xx < 0 || xx >= Ww) return 0.0f;
        return p[yy * Ww + xx];
    };

    float a00 = at(y - 1, x - 1), a01 = at(y - 1, x), a02 = at(y - 1, x + 1);
    float a10 = at(y,     x - 1),                     a12 = at(y,     x + 1);
    float a20 = at(y + 1, x - 1), a21 = at(y + 1, x), a22 = at(y + 1, x + 1);

    // JAX conv = cross-correlation, no kernel flip.
    float gx = (a02 - a00) + 2.0f * (a12 - a10) + (a22 - a20);
    float gy = (a20 - a00) + 2.0f * (a21 - a01) + (a22 - a02);

    float m = sqrtf(gx * gx + gy * gy);
    mag[id] = m;
    float inv = (m == 0.0f) ? 1.0f : (1.0f / m);
    tang[id] = make_float2(-gy * inv, gx * inv);

    // per-block max -> partials (NO global atomic: 32768 same-address
    // atomics serialized at ~10ns each was 376us in R0)
    float v = m;
    #pragma unroll
    for (int off = 32; off; off >>= 1) v = fmaxf(v, __shfl_xor(v, off));
    __shared__ float smax[4];
    int lane = threadIdx.x & 63, wid = threadIdx.x >> 6;
    if (lane == 0) smax[wid] = v;
    __syncthreads();
    if (threadIdx.x == 0) {
        partials[blockIdx.x] = fmaxf(fmaxf(smax[0], smax[1]), fmaxf(smax[2], smax[3]));
    }
}

__global__ void max_reduce_kernel(const float* __restrict__ partials,
                                  float* __restrict__ scale_out) {
    float v = 0.0f;
    for (int i = threadIdx.x; i < SOBEL_BLOCKS; i += 1024)
        v = fmaxf(v, partials[i]);
    #pragma unroll
    for (int off = 32; off; off >>= 1) v = fmaxf(v, __shfl_xor(v, off));
    __shared__ float smax[16];
    int lane = threadIdx.x & 63, wid = threadIdx.x >> 6;
    if (lane == 0) smax[wid] = v;
    __syncthreads();
    if (threadIdx.x == 0) {
        float m = smax[0];
        #pragma unroll
        for (int i = 1; i < 16; ++i) m = fmaxf(m, smax[i]);
        *scale_out = 1.0f / m;
    }
}

template <int DY, int DX, bool NORM, bool FINAL>
__global__ void etf_pass(const float2* __restrict__ src,
                         float2* __restrict__ dstI,
                         float* __restrict__ dstP,
                         const float* __restrict__ mag,
                         const float* __restrict__ scalep) {
    int id = blockIdx.x * blockDim.x + threadIdx.x;
    float scale = *scalep;
    int x = id & (Ww - 1);
    int y = (id >> 10) & (Hh - 1);
    int b = id >> 20;
    int base = b * (Hh * Ww);

    float2 tX = src[id];
    float mX = mag[id];
    float accx = 0.0f, accy = 0.0f;

    #pragma unroll
    for (int i = -MU; i <= MU; ++i) {
        int yy = y + i * DY;
        int xx = x + i * DX;
        if (yy < 0 || yy >= Hh || xx < 0 || xx >= Ww) continue;
        int j = base + yy * Ww + xx;
        float2 tY = src[j];
        float mY = mag[j];
        float d = tX.x * tY.x + tX.y * tY.y;
        float w = (fast_tanh(scale * (mY - mX)) + 1.0f) * d * 0.5f;
        accx += tY.x * w;
        accy += tY.y * w;
    }

    if (NORM) {
        float n = sqrtf(accx * accx + accy * accy);
        float inv = (n == 0.0f) ? 1.0f : (1.0f / n);
        accx *= inv;
        accy *= inv;
    }

    if (FINAL) {
        dstP[((size_t)(b * 2 + 0) * Hh + y) * Ww + x] = accx;
        dstP[((size_t)(b * 2 + 1) * Hh + y) * Ww + x] = accy;
    } else {
        dstI[id] = make_float2(accx, accy);
    }
}

extern "C" void kernel_launch(void* const* d_in, const int* in_sizes, int n_in,
                              void* d_out, int out_size, void* d_ws, size_t ws_size,
                              hipStream_t stream) {
    const float* in = (const float*)d_in[0];
    float* out = (float*)d_out;
    char* ws = (char*)d_ws;

    float* mag = (float*)ws;                                            // 32 MB
    float2* tA = (float2*)(ws + (size_t)NPIX * sizeof(float));          // 64 MB
    float* partials = (float*)(ws + (size_t)NPIX * sizeof(float)
                                  + (size_t)NPIX * sizeof(float2));     // 128 KB
    float* scalep = partials + SOBEL_BLOCKS;
    float2* tOut = (float2*)out;

    const int threads = SOBEL_THREADS;
    const int blocks = SOBEL_BLOCKS;

    sobel_kernel<<<blocks, threads, 0, stream>>>(in, tOut, mag, partials);
    max_reduce_kernel<<<1, 1024, 0, stream>>>(partials, scalep);

    // iteration 1
    etf_pass<1, 0, false, false><<<blocks, threads, 0, stream>>>(tOut, tA, nullptr, mag, scalep);
    etf_pass<0, 1, true,  false><<<blocks, threads, 0, stream>>>(tA, tOut, nullptr, mag, scalep);
    // iteration 2
    etf_pass<1, 0, false, false><<<blocks, threads, 0, stream>>>(tOut, tA, nullptr, mag, scalep);
    etf_pass<0, 1, true,  false><<<blocks, threads, 0, stream>>>(tA, tOut, nullptr, mag, scalep);
    // iteration 3
    etf_pass<1, 0, false, false><<<blocks, threads, 0, stream>>>(tOut, tA, nullptr, mag, scalep);
    etf_pass<0, 1, true,  true ><<<blocks, threads, 0, stream>>>(tA, nullptr, out, mag, scalep);
}

// Round 3
// 434.604 us; speedup vs baseline: 2.0695x; 1.2889x over previous
//
#include <hip/hip_runtime.h>

#define MU 5
static constexpr int Hh = 1024, Ww = 1024, Bb = 8;
static constexpr int NPIX = Bb * Hh * Ww;
static constexpr int TPB = 256;
static constexpr int NBLK = NPIX / TPB;   // 32768

__device__ __forceinline__ float rcp_fast(float x) { return __builtin_amdgcn_rcpf(x); }
__device__ __forceinline__ float rsq_fast(float x) { return __builtin_amdgcn_rsqf(x); }

__global__ void sobel_kernel(const float* __restrict__ in,
                             float2* __restrict__ tang,
                             float* __restrict__ mag,
                             float* __restrict__ partials) {
    int id = blockIdx.x * blockDim.x + threadIdx.x;
    int x = id & (Ww - 1);
    int y = (id >> 10) & (Hh - 1);
    int b = id >> 20;
    const float* p = in + (size_t)b * Hh * Ww;

    auto at = [&](int yy, int xx) -> float {
        if (yy < 0 || yy >= Hh || xx < 0 || xx >= Ww) return 0.0f;
        return p[yy * Ww + xx];
    };

    float a00 = at(y - 1, x - 1), a01 = at(y - 1, x), a02 = at(y - 1, x + 1);
    float a10 = at(y,     x - 1),                     a12 = at(y,     x + 1);
    float a20 = at(y + 1, x - 1), a21 = at(y + 1, x), a22 = at(y + 1, x + 1);

    float gx = (a02 - a00) + 2.0f * (a12 - a10) + (a22 - a20);
    float gy = (a20 - a00) + 2.0f * (a21 - a01) + (a22 - a02);

    float m = sqrtf(gx * gx + gy * gy);
    mag[id] = m;
    float inv = (m == 0.0f) ? 1.0f : (1.0f / m);
    tang[id] = make_float2(-gy * inv, gx * inv);

    float v = m;
    #pragma unroll
    for (int off = 32; off; off >>= 1) v = fmaxf(v, __shfl_xor(v, off));
    __shared__ float smax[4];
    int lane = threadIdx.x & 63, wid = threadIdx.x >> 6;
    if (lane == 0) smax[wid] = v;
    __syncthreads();
    if (threadIdx.x == 0)
        partials[blockIdx.x] = fmaxf(fmaxf(smax[0], smax[1]), fmaxf(smax[2], smax[3]));
}

__global__ void max_reduce_kernel(const float* __restrict__ partials,
                                  float* __restrict__ scale_out) {
    float v = 0.0f;
    for (int i = threadIdx.x; i < NBLK; i += 1024)
        v = fmaxf(v, partials[i]);
    #pragma unroll
    for (int off = 32; off; off >>= 1) v = fmaxf(v, __shfl_xor(v, off));
    __shared__ float smax[16];
    int lane = threadIdx.x & 63, wid = threadIdx.x >> 6;
    if (lane == 0) smax[wid] = v;
    __syncthreads();
    if (threadIdx.x == 0) {
        float m = smax[0];
        #pragma unroll
        for (int i = 1; i < 16; ++i) m = fmaxf(m, smax[i]);
        *scale_out = 1.0f / m;
    }
}

// In-place: mag[i] -> E[i] = exp(2*scale*mag[i]).  E in [1, e^2].
// Then per tap:  (tanh(scale*(mY-mX))+1)*0.5  ==  E_Y / (E_X + E_Y).
__global__ void prep_kernel(float4* __restrict__ mag4,
                            const float* __restrict__ scalep) {
    int id = blockIdx.x * blockDim.x + threadIdx.x;
    float k = 2.0f * (*scalep);
    float4 m = mag4[id];
    m.x = __expf(k * m.x);
    m.y = __expf(k * m.y);
    m.z = __expf(k * m.z);
    m.w = __expf(k * m.w);
    mag4[id] = m;
}

template <int STRIDE, bool CHECK>
__device__ __forceinline__ float2 etf_accum(const float2* __restrict__ src,
                                            const float* __restrict__ E,
                                            int id, int pos,
                                            float2 tX, float eX) {
    float accx = 0.0f, accy = 0.0f;
    #pragma unroll
    for (int i = -MU; i <= MU; ++i) {
        if (CHECK) {
            int pp = pos + i;
            if (pp < 0 || pp >= 1024) continue;
        }
        int j = id + i * STRIDE;
        float2 tY = src[j];
        float eY = E[j];
        float d = tX.x * tY.x + tX.y * tY.y;
        float w = eY * rcp_fast(eX + eY) * d;
        accx += tY.x * w;
        accy += tY.y * w;
    }
    return make_float2(accx, accy);
}

template <int DY, int DX, bool NORM, bool FINAL>
__global__ void etf_pass(const float2* __restrict__ src,
                         float2* __restrict__ dstI,
                         float* __restrict__ dstP,
                         const float* __restrict__ E) {
    int id = blockIdx.x * blockDim.x + threadIdx.x;
    int x = id & (Ww - 1);
    int y = (id >> 10) & (Hh - 1);

    float2 tX = src[id];
    float eX = E[id];

    constexpr int S = DY * Ww + DX;
    float2 acc;
    if (DY) {
        // whole block shares y -> uniform branch, no divergence
        if (y >= MU && y < Hh - MU)
            acc = etf_accum<S, false>(src, E, id, y, tX, eX);
        else
            acc = etf_accum<S, true>(src, E, id, y, tX, eX);
    } else {
        int xs = (blockIdx.x * TPB) & (Ww - 1);   // block's first column
        if (xs >= MU && xs + TPB - 1 + MU < Ww)
            acc = etf_accum<S, false>(src, E, id, x, tX, eX);
        else
            acc = etf_accum<S, true>(src, E, id, x, tX, eX);
    }

    if (NORM) {
        float n2 = acc.x * acc.x + acc.y * acc.y;
        float inv = (n2 > 0.0f) ? rsq_fast(n2) : 1.0f;
        acc.x *= inv;
        acc.y *= inv;
    }

    if (FINAL) {
        int b = id >> 20;
        dstP[((size_t)(b * 2 + 0) * Hh + y) * Ww + x] = acc.x;
        dstP[((size_t)(b * 2 + 1) * Hh + y) * Ww + x] = acc.y;
    } else {
        dstI[id] = acc;
    }
}

extern "C" void kernel_launch(void* const* d_in, const int* in_sizes, int n_in,
                              void* d_out, int out_size, void* d_ws, size_t ws_size,
                              hipStream_t stream) {
    const float* in = (const float*)d_in[0];
    float* out = (float*)d_out;
    char* ws = (char*)d_ws;

    float* magE = (float*)ws;                                           // 32 MB (mag, then E in place)
    float2* tA = (float2*)(ws + (size_t)NPIX * sizeof(float));          // 64 MB
    float* partials = (float*)(ws + (size_t)NPIX * sizeof(float)
                                  + (size_t)NPIX * sizeof(float2));     // 128 KB
    float* scalep = partials + NBLK;
    float2* tOut = (float2*)out;

    sobel_kernel<<<NBLK, TPB, 0, stream>>>(in, tOut, magE, partials);
    max_reduce_kernel<<<1, 1024, 0, stream>>>(partials, scalep);
    prep_kernel<<<NPIX / 4 / TPB, TPB, 0, stream>>>((float4*)magE, scalep);

    // iteration 1
    etf_pass<1, 0, false, false><<<NBLK, TPB, 0, stream>>>(tOut, tA, nullptr, magE);
    etf_pass<0, 1, true,  false><<<NBLK, TPB, 0, stream>>>(tA, tOut, nullptr, magE);
    // iteration 2
    etf_pass<1, 0, false, false><<<NBLK, TPB, 0, stream>>>(tOut, tA, nullptr, magE);
    etf_pass<0, 1, true,  false><<<NBLK, TPB, 0, stream>>>(tA, tOut, nullptr, magE);
    // iteration 3
    etf_pass<1, 0, false, false><<<NBLK, TPB, 0, stream>>>(tOut, tA, nullptr, magE);
    etf_pass<0, 1, true,  true ><<<NBLK, TPB, 0, stream>>>(tA, nullptr, out, magE);
}

// Round 4
// 249.547 us; speedup vs baseline: 3.6041x; 1.7416x over previous
//
#include <hip/hip_runtime.h>

#define MU 5
static constexpr int Hh = 1024, Ww = 1024, Bb = 8;
static constexpr int NPIX = Bb * Hh * Ww;
static constexpr int TPB = 256;
static constexpr int NBLK = NPIX / TPB;     // 32768 (sobel)
static constexpr int PY = 4, PX = 4;
static constexpr int PASS_BLOCKS = NPIX / PY / TPB;   // 8192 for both V and H

__device__ __forceinline__ float rcp_fast(float x) { return __builtin_amdgcn_rcpf(x); }
__device__ __forceinline__ float rsq_fast(float x) { return __builtin_amdgcn_rsqf(x); }

// Bijective XCD-chunk swizzle (8192 % 8 == 0): XCD k gets one contiguous
// chunk = one batch image, so stencil halos reuse within one L2.
__device__ __forceinline__ int xcd_swizzle(int bid) {
    return (bid & 7) * (PASS_BLOCKS / 8) + (bid >> 3);
}

__global__ void sobel_kernel(const float* __restrict__ in,
                             float2* __restrict__ tang,
                             float* __restrict__ mag,
                             float* __restrict__ partials) {
    int id = blockIdx.x * blockDim.x + threadIdx.x;
    int x = id & (Ww - 1);
    int y = (id >> 10) & (Hh - 1);
    int b = id >> 20;
    const float* p = in + (size_t)b * Hh * Ww;

    auto at = [&](int yy, int xx) -> float {
        if (yy < 0 || yy >= Hh || xx < 0 || xx >= Ww) return 0.0f;
        return p[yy * Ww + xx];
    };

    float a00 = at(y - 1, x - 1), a01 = at(y - 1, x), a02 = at(y - 1, x + 1);
    float a10 = at(y,     x - 1),                     a12 = at(y,     x + 1);
    float a20 = at(y + 1, x - 1), a21 = at(y + 1, x), a22 = at(y + 1, x + 1);

    float gx = (a02 - a00) + 2.0f * (a12 - a10) + (a22 - a20);
    float gy = (a20 - a00) + 2.0f * (a21 - a01) + (a22 - a02);

    float m = sqrtf(gx * gx + gy * gy);
    mag[id] = m;
    float inv = (m == 0.0f) ? 1.0f : (1.0f / m);
    tang[id] = make_float2(-gy * inv, gx * inv);

    float v = m;
    #pragma unroll
    for (int off = 32; off; off >>= 1) v = fmaxf(v, __shfl_xor(v, off));
    __shared__ float smax[4];
    int lane = threadIdx.x & 63, wid = threadIdx.x >> 6;
    if (lane == 0) smax[wid] = v;
    __syncthreads();
    if (threadIdx.x == 0)
        partials[blockIdx.x] = fmaxf(fmaxf(smax[0], smax[1]), fmaxf(smax[2], smax[3]));
}

__global__ void max_reduce_kernel(const float* __restrict__ partials,
                                  float* __restrict__ scale_out) {
    float v = 0.0f;
    for (int i = threadIdx.x; i < NBLK; i += 1024)
        v = fmaxf(v, partials[i]);
    #pragma unroll
    for (int off = 32; off; off >>= 1) v = fmaxf(v, __shfl_xor(v, off));
    __shared__ float smax[16];
    int lane = threadIdx.x & 63, wid = threadIdx.x >> 6;
    if (lane == 0) smax[wid] = v;
    __syncthreads();
    if (threadIdx.x == 0) {
        float m = smax[0];
        #pragma unroll
        for (int i = 1; i < 16; ++i) m = fmaxf(m, smax[i]);
        *scale_out = 1.0f / m;
    }
}

// In-place: mag -> E = exp(2*scale*mag), E in [1, e^2].
// Per tap: (tanh(scale*(mY-mX))+1)*0.5 == E_Y / (E_X + E_Y).
__global__ void prep_kernel(float4* __restrict__ mag4,
                            const float* __restrict__ scalep) {
    int id = blockIdx.x * blockDim.x + threadIdx.x;
    float k = 2.0f * (*scalep);
    float4 m = mag4[id];
    m.x = __expf(k * m.x);
    m.y = __expf(k * m.y);
    m.z = __expf(k * m.z);
    m.w = __expf(k * m.w);
    mag4[id] = m;
}

// ---- V pass: each thread computes PY=4 vertically-consecutive outputs ----
__global__ void etf_v(const float2* __restrict__ src,
                      float2* __restrict__ dst,
                      const float* __restrict__ E) {
    int bid = xcd_swizzle((int)blockIdx.x);
    int gid = bid * TPB + threadIdx.x;
    int x = gid & (Ww - 1);
    int rest = gid >> 10;
    int yg = rest & 255;
    int b = rest >> 8;
    int y0 = yg * PY;
    int base = b << 20;

    float2 t[PY + 10];
    float  e[PY + 10];
    if (yg >= 2 && yg <= 253) {            // uniform per block
        #pragma unroll
        for (int r = 0; r < PY + 10; ++r) {
            int j = base + (y0 - MU + r) * Ww + x;
            t[r] = src[j];
            e[r] = E[j];
        }
    } else {
        #pragma unroll
        for (int r = 0; r < PY + 10; ++r) {
            int row = y0 - MU + r;
            bool ok = (row >= 0) && (row < Hh);
            int j = base + (ok ? row : 0) * Ww + x;
            t[r] = ok ? src[j] : make_float2(0.0f, 0.0f);
            e[r] = ok ? E[j] : 1.0f;       // d=0 anyway; keep rcp finite
        }
    }

    #pragma unroll
    for (int k = 0; k < PY; ++k) {
        float2 tX = t[k + MU];
        float  eX = e[k + MU];
        float ax = 0.0f, ay = 0.0f;
        #pragma unroll
        for (int i = 0; i <= 2 * MU; ++i) {
            float2 tY = t[k + i];
            float  eY = e[k + i];
            float d = tX.x * tY.x + tX.y * tY.y;
            float w = eY * rcp_fast(eX + eY) * d;
            ax += tY.x * w;
            ay += tY.y * w;
        }
        dst[base + (y0 + k) * Ww + x] = make_float2(ax, ay);
    }
}

// ---- H pass: each thread computes PX=4 horizontally-consecutive outputs ----
template <bool FINAL>
__global__ void etf_h(const float2* __restrict__ src,
                      float2* __restrict__ dstI,
                      float* __restrict__ dstP,
                      const float* __restrict__ E) {
    int bid = xcd_swizzle((int)blockIdx.x);
    int gid = bid * TPB + threadIdx.x;
    int xq = gid & 255;
    int x0 = xq * PX;
    int y = (gid >> 8) & (Hh - 1);
    int b = gid >> 18;
    int rowbase = (b << 20) + y * Ww;

    float2 t[PX + 10];
    float  e[PX + 10];
    if (xq >= 2 && xq <= 253) {            // only waves 0/3 of a block diverge
        #pragma unroll
        for (int r = 0; r < PX + 10; ++r) {
            int j = rowbase + x0 - MU + r;
            t[r] = src[j];
            e[r] = E[j];
        }
    } else {
        #pragma unroll
        for (int r = 0; r < PX + 10; ++r) {
            int col = x0 - MU + r;
            bool ok = (col >= 0) && (col < Ww);
            int j = rowbase + (ok ? col : 0);
            t[r] = ok ? src[j] : make_float2(0.0f, 0.0f);
            e[r] = ok ? E[j] : 1.0f;
        }
    }

    float ox[PX], oy[PX];
    #pragma unroll
    for (int k = 0; k < PX; ++k) {
        float2 tX = t[k + MU];
        float  eX = e[k + MU];
        float ax = 0.0f, ay = 0.0f;
        #pragma unroll
        for (int i = 0; i <= 2 * MU; ++i) {
            float2 tY = t[k + i];
            float  eY = e[k + i];
            float d = tX.x * tY.x + tX.y * tY.y;
            float w = eY * rcp_fast(eX + eY) * d;
            ax += tY.x * w;
            ay += tY.y * w;
        }
        // normalize (H pass ends each iteration)
        float n2 = ax * ax + ay * ay;
        float inv = (n2 > 0.0f) ? rsq_fast(n2) : 1.0f;
        ox[k] = ax * inv;
        oy[k] = ay * inv;
    }

    if (FINAL) {
        *(float4*)&dstP[((size_t)(b * 2 + 0) << 20) + y * Ww + x0] =
            make_float4(ox[0], ox[1], ox[2], ox[3]);
        *(float4*)&dstP[((size_t)(b * 2 + 1) << 20) + y * Ww + x0] =
            make_float4(oy[0], oy[1], oy[2], oy[3]);
    } else {
        float4* dp = (float4*)&dstI[rowbase + x0];
        dp[0] = make_float4(ox[0], oy[0], ox[1], oy[1]);
        dp[1] = make_float4(ox[2], oy[2], ox[3], oy[3]);
    }
}

extern "C" void kernel_launch(void* const* d_in, const int* in_sizes, int n_in,
                              void* d_out, int out_size, void* d_ws, size_t ws_size,
                              hipStream_t stream) {
    const float* in = (const float*)d_in[0];
    float* out = (float*)d_out;
    char* ws = (char*)d_ws;

    float* magE = (float*)ws;                                           // 32 MB
    float2* tA = (float2*)(ws + (size_t)NPIX * sizeof(float));          // 64 MB
    float* partials = (float*)(ws + (size_t)NPIX * sizeof(float)
                                  + (size_t)NPIX * sizeof(float2));     // 128 KB
    float* scalep = partials + NBLK;
    float2* tOut = (float2*)out;

    sobel_kernel<<<NBLK, TPB, 0, stream>>>(in, tOut, magE, partials);
    max_reduce_kernel<<<1, 1024, 0, stream>>>(partials, scalep);
    prep_kernel<<<NPIX / 4 / TPB, TPB, 0, stream>>>((float4*)magE, scalep);

    // iteration 1
    etf_v<<<PASS_BLOCKS, TPB, 0, stream>>>(tOut, tA, magE);
    etf_h<false><<<PASS_BLOCKS, TPB, 0, stream>>>(tA, tOut, nullptr, magE);
    // iteration 2
    etf_v<<<PASS_BLOCKS, TPB, 0, stream>>>(tOut, tA, magE);
    etf_h<false><<<PASS_BLOCKS, TPB, 0, stream>>>(tA, tOut, nullptr, magE);
    // iteration 3
    etf_v<<<PASS_BLOCKS, TPB, 0, stream>>>(tOut, tA, magE);
    etf_h<true ><<<PASS_BLOCKS, TPB, 0, stream>>>(tA, nullptr, out, magE);
}

// Round 5
// 235.542 us; speedup vs baseline: 3.8184x; 1.0595x over previous
//
#include <hip/hip_runtime.h>

#define MU 5
static constexpr int Hh = 1024, Ww = 1024, Bb = 8;
static constexpr int NPIX = Bb * Hh * Ww;
static constexpr int TPB = 256;
static constexpr int SPY = 4;
static constexpr int SOBEL_BLOCKS = NPIX / SPY / TPB;   // 8192
static constexpr int PY = 8, PX = 8;
static constexpr int VBLK = NPIX / PY / TPB;            // 4096
static constexpr int HBLK = NPIX / PX / TPB;            // 4096

__device__ __forceinline__ float rcp_fast(float x) { return __builtin_amdgcn_rcpf(x); }
__device__ __forceinline__ float rsq_fast(float x) { return __builtin_amdgcn_rsqf(x); }

// Bijective XCD-chunk swizzle (4096 % 8 == 0, chunk 512 = one batch image
// per XCD): stencil halo reuse stays within one XCD's L2.
template <int NB>
__device__ __forceinline__ int xcd_swizzle(int bid) {
    return (bid & 7) * (NB / 8) + (bid >> 3);
}

// ---- Sobel: 4 rows per thread, shared row-differences, v_rsq ----
__global__ __launch_bounds__(TPB) void sobel_kernel(
        const float* __restrict__ in, float2* __restrict__ tang,
        float* __restrict__ mag, float* __restrict__ partials) {
    int id = blockIdx.x * TPB + threadIdx.x;
    int x = id & (Ww - 1);
    int yg = (id >> 10) & (Hh / SPY - 1);
    int b = id >> 18;
    int y0 = yg * SPY;
    const float* p = in + ((size_t)b << 20);

    float a[SPY + 2][3];
    bool cl = (x > 0), cr = (x < Ww - 1);
    if (yg >= 1 && yg <= Hh / SPY - 2) {        // uniform per block
        #pragma unroll
        for (int r = 0; r < SPY + 2; ++r) {
            const float* row = p + (y0 - 1 + r) * Ww + x;
            a[r][0] = cl ? row[-1] : 0.0f;
            a[r][1] = row[0];
            a[r][2] = cr ? row[1] : 0.0f;
        }
    } else {
        #pragma unroll
        for (int r = 0; r < SPY + 2; ++r) {
            int yy = y0 - 1 + r;
            bool okr = (yy >= 0) && (yy < Hh);
            const float* row = p + (okr ? yy : 0) * Ww + x;
            a[r][0] = (okr && cl) ? row[-1] : 0.0f;
            a[r][1] = okr ? row[0] : 0.0f;
            a[r][2] = (okr && cr) ? row[1] : 0.0f;
        }
    }

    float s[SPY + 2];
    #pragma unroll
    for (int r = 0; r < SPY + 2; ++r) s[r] = a[r][2] - a[r][0];

    float vmax = 0.0f;
    #pragma unroll
    for (int k = 0; k < SPY; ++k) {
        float gx = s[k] + 2.0f * s[k + 1] + s[k + 2];
        float u1 = a[k + 2][0] - a[k][0];
        float u2 = a[k + 2][1] - a[k][1];
        float u3 = a[k + 2][2] - a[k][2];
        float gy = u1 + 2.0f * u2 + u3;
        float g2 = gx * gx + gy * gy;
        float irs = rsq_fast(g2);
        float m   = (g2 > 0.0f) ? g2 * irs : 0.0f;   // sqrt(g2)
        float inv = (g2 > 0.0f) ? irs : 1.0f;        // 1/sqrt(g2)
        int j = (b << 20) + (y0 + k) * Ww + x;
        mag[j] = m;
        tang[j] = make_float2(-gy * inv, gx * inv);
        vmax = fmaxf(vmax, m);
    }

    #pragma unroll
    for (int off = 32; off; off >>= 1) vmax = fmaxf(vmax, __shfl_xor(vmax, off));
    __shared__ float smax[4];
    int lane = threadIdx.x & 63, wid = threadIdx.x >> 6;
    if (lane == 0) smax[wid] = vmax;
    __syncthreads();
    if (threadIdx.x == 0)
        partials[blockIdx.x] = fmaxf(fmaxf(smax[0], smax[1]), fmaxf(smax[2], smax[3]));
}

__global__ void max_reduce_kernel(const float* __restrict__ partials,
                                  float* __restrict__ scale_out) {
    float v = 0.0f;
    for (int i = threadIdx.x; i < SOBEL_BLOCKS; i += 1024)
        v = fmaxf(v, partials[i]);
    #pragma unroll
    for (int off = 32; off; off >>= 1) v = fmaxf(v, __shfl_xor(v, off));
    __shared__ float smax[16];
    int lane = threadIdx.x & 63, wid = threadIdx.x >> 6;
    if (lane == 0) smax[wid] = v;
    __syncthreads();
    if (threadIdx.x == 0) {
        float m = smax[0];
        #pragma unroll
        for (int i = 1; i < 16; ++i) m = fmaxf(m, smax[i]);
        *scale_out = 1.0f / m;
    }
}

// In-place: mag -> E = exp(2*scale*mag), E in [1, e^2].
// Per tap: (tanh(scale*(mY-mX))+1)*0.5 == E_Y / (E_X + E_Y).
__global__ void prep_kernel(float4* __restrict__ mag4,
                            const float* __restrict__ scalep) {
    int id = blockIdx.x * blockDim.x + threadIdx.x;
    float k = 2.0f * (*scalep);
    float4 m = mag4[id];
    m.x = __expf(k * m.x);
    m.y = __expf(k * m.y);
    m.z = __expf(k * m.z);
    m.w = __expf(k * m.w);
    mag4[id] = m;
}

// ---- V pass: PY=8 vertically-consecutive outputs per thread ----
__global__ __launch_bounds__(TPB) void etf_v(const float2* __restrict__ src,
                                             float2* __restrict__ dst,
                                             const float* __restrict__ E) {
    int bid = xcd_swizzle<VBLK>((int)blockIdx.x);
    int gid = bid * TPB + threadIdx.x;
    int x = gid & (Ww - 1);
    int yg = (gid >> 10) & (Hh / PY - 1);
    int b = gid >> 17;
    int y0 = yg * PY;
    int base = b << 20;

    float2 t[PY + 10];
    float  e[PY + 10];
    if (yg >= 1 && yg <= Hh / PY - 2) {          // uniform per block
        #pragma unroll
        for (int r = 0; r < PY + 10; ++r) {
            int j = base + (y0 - MU + r) * Ww + x;
            t[r] = src[j];
            e[r] = E[j];
        }
    } else {
        #pragma unroll
        for (int r = 0; r < PY + 10; ++r) {
            int row = y0 - MU + r;
            bool ok = (row >= 0) && (row < Hh);
            int j = base + (ok ? row : 0) * Ww + x;
            t[r] = ok ? src[j] : make_float2(0.0f, 0.0f);
            e[r] = ok ? E[j] : 1.0f;             // d=0 anyway; keep rcp finite
        }
    }

    #pragma unroll
    for (int k = 0; k < PY; ++k) {
        float2 tX = t[k + MU];
        float  eX = e[k + MU];
        float ax = 0.0f, ay = 0.0f;
        #pragma unroll
        for (int i = 0; i <= 2 * MU; ++i) {
            float2 tY = t[k + i];
            float  eY = e[k + i];
            float d = tX.x * tY.x + tX.y * tY.y;
            float w = eY * rcp_fast(eX + eY) * d;
            ax += tY.x * w;
            ay += tY.y * w;
        }
        dst[base + (y0 + k) * Ww + x] = make_float2(ax, ay);
    }
}

// ---- H pass: PX=8 horizontally-consecutive outputs per thread ----
template <bool FINAL>
__global__ __launch_bounds__(TPB) void etf_h(const float2* __restrict__ src,
                                             float2* __restrict__ dstI,
                                             float* __restrict__ dstP,
                                             const float* __restrict__ E) {
    int bid = xcd_swizzle<HBLK>((int)blockIdx.x);
    int gid = bid * TPB + threadIdx.x;
    int xq = gid & (Ww / PX - 1);
    int x0 = xq * PX;
    int y = (gid >> 7) & (Hh - 1);
    int b = gid >> 17;
    int rowbase = (b << 20) + y * Ww;

    float2 t[PX + 10];
    float  e[PX + 10];
    if (xq >= 1 && xq <= Ww / PX - 2) {
        #pragma unroll
        for (int r = 0; r < PX + 10; ++r) {
            int j = rowbase + x0 - MU + r;
            t[r] = src[j];
            e[r] = E[j];
        }
    } else {
        #pragma unroll
        for (int r = 0; r < PX + 10; ++r) {
            int col = x0 - MU + r;
            bool ok = (col >= 0) && (col < Ww);
            int j = rowbase + (ok ? col : 0);
            t[r] = ok ? src[j] : make_float2(0.0f, 0.0f);
            e[r] = ok ? E[j] : 1.0f;
        }
    }

    float ox[PX], oy[PX];
    #pragma unroll
    for (int k = 0; k < PX; ++k) {
        float2 tX = t[k + MU];
        float  eX = e[k + MU];
        float ax = 0.0f, ay = 0.0f;
        #pragma unroll
        for (int i = 0; i <= 2 * MU; ++i) {
            float2 tY = t[k + i];
            float  eY = e[k + i];
            float d = tX.x * tY.x + tX.y * tY.y;
            float w = eY * rcp_fast(eX + eY) * d;
            ax += tY.x * w;
            ay += tY.y * w;
        }
        float n2 = ax * ax + ay * ay;
        float inv = (n2 > 0.0f) ? rsq_fast(n2) : 1.0f;
        ox[k] = ax * inv;
        oy[k] = ay * inv;
    }

    if (FINAL) {
        float4* px = (float4*)&dstP[((size_t)(b * 2 + 0) << 20) + y * Ww + x0];
        px[0] = make_float4(ox[0], ox[1], ox[2], ox[3]);
        px[1] = make_float4(ox[4], ox[5], ox[6], ox[7]);
        float4* py = (float4*)&dstP[((size_t)(b * 2 + 1) << 20) + y * Ww + x0];
        py[0] = make_float4(oy[0], oy[1], oy[2], oy[3]);
        py[1] = make_float4(oy[4], oy[5], oy[6], oy[7]);
    } else {
        float4* dp = (float4*)&dstI[rowbase + x0];
        dp[0] = make_float4(ox[0], oy[0], ox[1], oy[1]);
        dp[1] = make_float4(ox[2], oy[2], ox[3], oy[3]);
        dp[2] = make_float4(ox[4], oy[4], ox[5], oy[5]);
        dp[3] = make_float4(ox[6], oy[6], ox[7], oy[7]);
    }
}

extern "C" void kernel_launch(void* const* d_in, const int* in_sizes, int n_in,
                              void* d_out, int out_size, void* d_ws, size_t ws_size,
                              hipStream_t stream) {
    const float* in = (const float*)d_in[0];
    float* out = (float*)d_out;
    char* ws = (char*)d_ws;

    float* magE = (float*)ws;                                           // 32 MB
    float2* tA = (float2*)(ws + (size_t)NPIX * sizeof(float));          // 64 MB
    float* partials = (float*)(ws + (size_t)NPIX * sizeof(float)
                                  + (size_t)NPIX * sizeof(float2));
    float* scalep = partials + SOBEL_BLOCKS;
    float2* tOut = (float2*)out;

    sobel_kernel<<<SOBEL_BLOCKS, TPB, 0, stream>>>(in, tOut, magE, partials);
    max_reduce_kernel<<<1, 1024, 0, stream>>>(partials, scalep);
    prep_kernel<<<NPIX / 4 / TPB, TPB, 0, stream>>>((float4*)magE, scalep);

    // iteration 1
    etf_v<<<VBLK, TPB, 0, stream>>>(tOut, tA, magE);
    etf_h<false><<<HBLK, TPB, 0, stream>>>(tA, tOut, nullptr, magE);
    // iteration 2
    etf_v<<<VBLK, TPB, 0, stream>>>(tOut, tA, magE);
    etf_h<false><<<HBLK, TPB, 0, stream>>>(tA, tOut, nullptr, magE);
    // iteration 3
    etf_v<<<VBLK, TPB, 0, stream>>>(tOut, tA, magE);
    etf_h<true ><<<HBLK, TPB, 0, stream>>>(tA, nullptr, out, magE);
}

// Round 6
// 232.850 us; speedup vs baseline: 3.8626x; 1.0116x over previous
//
#include <hip/hip_runtime.h>

#define MU 5
static constexpr int Hh = 1024, Ww = 1024, Bb = 8;
static constexpr int NPIX = Bb * Hh * Ww;
static constexpr int TPB = 256;
static constexpr int SPY = 4;
static constexpr int SOBEL_BLOCKS = NPIX / SPY / TPB;   // 8192
static constexpr int PY = 8, PX = 8;
static constexpr int VBLK = NPIX / PY / TPB;            // 4096
static constexpr int HBLK = NPIX / PX / TPB;            // 4096

__device__ __forceinline__ float rcp_fast(float x) { return __builtin_amdgcn_rcpf(x); }
__device__ __forceinline__ float rsq_fast(float x) { return __builtin_amdgcn_rsqf(x); }

// Bijective XCD-chunk swizzle (4096 % 8 == 0, chunk 512 = one batch image
// per XCD): stencil halo reuse stays within one XCD's L2.
template <int NB>
__device__ __forceinline__ int xcd_swizzle(int bid) {
    return (bid & 7) * (NB / 8) + (bid >> 3);
}

// ---- Sobel: 4 rows per thread, shared row-differences, v_rsq ----
__global__ __launch_bounds__(TPB) void sobel_kernel(
        const float* __restrict__ in, float2* __restrict__ tang,
        float* __restrict__ mag, float* __restrict__ partials) {
    int id = blockIdx.x * TPB + threadIdx.x;
    int x = id & (Ww - 1);
    int yg = (id >> 10) & (Hh / SPY - 1);
    int b = id >> 18;
    int y0 = yg * SPY;
    const float* p = in + ((size_t)b << 20);

    float a[SPY + 2][3];
    bool cl = (x > 0), cr = (x < Ww - 1);
    if (yg >= 1 && yg <= Hh / SPY - 2) {        // uniform per block
        #pragma unroll
        for (int r = 0; r < SPY + 2; ++r) {
            const float* row = p + (y0 - 1 + r) * Ww + x;
            a[r][0] = cl ? row[-1] : 0.0f;
            a[r][1] = row[0];
            a[r][2] = cr ? row[1] : 0.0f;
        }
    } else {
        #pragma unroll
        for (int r = 0; r < SPY + 2; ++r) {
            int yy = y0 - 1 + r;
            bool okr = (yy >= 0) && (yy < Hh);
            const float* row = p + (okr ? yy : 0) * Ww + x;
            a[r][0] = (okr && cl) ? row[-1] : 0.0f;
            a[r][1] = okr ? row[0] : 0.0f;
            a[r][2] = (okr && cr) ? row[1] : 0.0f;
        }
    }

    float s[SPY + 2];
    #pragma unroll
    for (int r = 0; r < SPY + 2; ++r) s[r] = a[r][2] - a[r][0];

    float vmax = 0.0f;
    #pragma unroll
    for (int k = 0; k < SPY; ++k) {
        float gx = s[k] + 2.0f * s[k + 1] + s[k + 2];
        float u1 = a[k + 2][0] - a[k][0];
        float u2 = a[k + 2][1] - a[k][1];
        float u3 = a[k + 2][2] - a[k][2];
        float gy = u1 + 2.0f * u2 + u3;
        float g2 = gx * gx + gy * gy;
        float irs = rsq_fast(g2);
        float m   = (g2 > 0.0f) ? g2 * irs : 0.0f;   // sqrt(g2)
        float inv = (g2 > 0.0f) ? irs : 1.0f;        // 1/sqrt(g2)
        int j = (b << 20) + (y0 + k) * Ww + x;
        mag[j] = m;
        tang[j] = make_float2(-gy * inv, gx * inv);
        vmax = fmaxf(vmax, m);
    }

    #pragma unroll
    for (int off = 32; off; off >>= 1) vmax = fmaxf(vmax, __shfl_xor(vmax, off));
    __shared__ float smax[4];
    int lane = threadIdx.x & 63, wid = threadIdx.x >> 6;
    if (lane == 0) smax[wid] = vmax;
    __syncthreads();
    if (threadIdx.x == 0)
        partials[blockIdx.x] = fmaxf(fmaxf(smax[0], smax[1]), fmaxf(smax[2], smax[3]));
}

__global__ void max_reduce_kernel(const float* __restrict__ partials,
                                  float* __restrict__ scale_out) {
    float v = 0.0f;
    for (int i = threadIdx.x; i < SOBEL_BLOCKS; i += 1024)
        v = fmaxf(v, partials[i]);
    #pragma unroll
    for (int off = 32; off; off >>= 1) v = fmaxf(v, __shfl_xor(v, off));
    __shared__ float smax[16];
    int lane = threadIdx.x & 63, wid = threadIdx.x >> 6;
    if (lane == 0) smax[wid] = v;
    __syncthreads();
    if (threadIdx.x == 0) {
        float m = smax[0];
        #pragma unroll
        for (int i = 1; i < 16; ++i) m = fmaxf(m, smax[i]);
        *scale_out = 1.0f / m;
    }
}

// In-place: mag -> E = exp(2*scale*mag), E in [1, e^2].
// Per tap: (tanh(scale*(mY-mX))+1)*0.5 == E_Y / (E_X + E_Y).
__global__ void prep_kernel(float4* __restrict__ mag4,
                            const float* __restrict__ scalep) {
    int id = blockIdx.x * blockDim.x + threadIdx.x;
    float k = 2.0f * (*scalep);
    float4 m = mag4[id];
    m.x = __expf(k * m.x);
    m.y = __expf(k * m.y);
    m.z = __expf(k * m.z);
    m.w = __expf(k * m.w);
    mag4[id] = m;
}

// ---- V pass: PY=8 vertically-consecutive outputs per thread ----
__global__ __launch_bounds__(TPB) void etf_v(const float2* __restrict__ src,
                                             float2* __restrict__ dst,
                                             const float* __restrict__ E) {
    int bid = xcd_swizzle<VBLK>((int)blockIdx.x);
    int gid = bid * TPB + threadIdx.x;
    int x = gid & (Ww - 1);
    int yg = (gid >> 10) & (Hh / PY - 1);
    int b = gid >> 17;
    int y0 = yg * PY;
    int base = b << 20;

    float2 t[PY + 10];
    float  e[PY + 10];
    if (yg >= 1 && yg <= Hh / PY - 2) {          // uniform per block
        #pragma unroll
        for (int r = 0; r < PY + 10; ++r) {
            int j = base + (y0 - MU + r) * Ww + x;
            t[r] = src[j];
            e[r] = E[j];
        }
    } else {
        #pragma unroll
        for (int r = 0; r < PY + 10; ++r) {
            int row = y0 - MU + r;
            bool ok = (row >= 0) && (row < Hh);
            int j = base + (ok ? row : 0) * Ww + x;
            t[r] = ok ? src[j] : make_float2(0.0f, 0.0f);
            e[r] = ok ? E[j] : 1.0f;             // d=0 anyway; keep rcp finite
        }
    }

    #pragma unroll
    for (int k = 0; k < PY; ++k) {
        float2 tX = t[k + MU];
        float  eX = e[k + MU];
        float ax = 0.0f, ay = 0.0f;
        #pragma unroll
        for (int i = 0; i <= 2 * MU; ++i) {
            float2 tY = t[k + i];
            float  eY = e[k + i];
            float d = tX.x * tY.x + tX.y * tY.y;
            float w = eY * rcp_fast(eX + eY) * d;
            ax += tY.x * w;
            ay += tY.y * w;
        }
        dst[base + (y0 + k) * Ww + x] = make_float2(ax, ay);
    }
}

// ---- H pass: PX=8 outputs per thread, float4-vectorized 24-wide window ----
// Interior threads load the 64B-aligned window [x0-8, x0+16) as 12+6 float4
// (R4's scalar float2 gather at lane-stride 64B was TA-bound: 64 cache lines
// per wave-instruction).
template <bool FINAL>
__global__ __launch_bounds__(TPB) void etf_h(const float2* __restrict__ src,
                                             float2* __restrict__ dstI,
                                             float* __restrict__ dstP,
                                             const float* __restrict__ E) {
    int bid = xcd_swizzle<HBLK>((int)blockIdx.x);
    int gid = bid * TPB + threadIdx.x;
    int xq = gid & (Ww / PX - 1);        // 0..127
    int x0 = xq * PX;
    int y = (gid >> 7) & (Hh - 1);
    int b = gid >> 17;
    int rowbase = (b << 20) + y * Ww;

    float2 t[PX + 16];                   // window [x0-8, x0+16)
    float  e[PX + 16];
    if (xq >= 1 && xq <= Ww / PX - 2) {  // interior: in-row, aligned
        const float4* tp = (const float4*)&src[rowbase + x0 - 8];
        #pragma unroll
        for (int m = 0; m < 12; ++m) {
            float4 v = tp[m];
            t[2 * m]     = make_float2(v.x, v.y);
            t[2 * m + 1] = make_float2(v.z, v.w);
        }
        const float4* ep = (const float4*)&E[rowbase + x0 - 8];
        #pragma unroll
        for (int m = 0; m < 6; ++m) {
            float4 v = ep[m];
            e[4 * m]     = v.x;
            e[4 * m + 1] = v.y;
            e[4 * m + 2] = v.z;
            e[4 * m + 3] = v.w;
        }
    } else {                             // border: masked scalar path
        #pragma unroll
        for (int r = 0; r < PX + 16; ++r) {
            int col = x0 - 8 + r;
            bool ok = (col >= 0) && (col < Ww);
            int j = rowbase + (ok ? col : 0);
            t[r] = ok ? src[j] : make_float2(0.0f, 0.0f);
            e[r] = ok ? E[j] : 1.0f;
        }
    }

    float ox[PX], oy[PX];
    #pragma unroll
    for (int k = 0; k < PX; ++k) {
        float2 tX = t[k + 8];
        float  eX = e[k + 8];
        float ax = 0.0f, ay = 0.0f;
        #pragma unroll
        for (int i = 0; i <= 2 * MU; ++i) {   // tap col = x0+k-5+i -> idx k+i+3
            float2 tY = t[k + i + 3];
            float  eY = e[k + i + 3];
            float d = tX.x * tY.x + tX.y * tY.y;
            float w = eY * rcp_fast(eX + eY) * d;
            ax += tY.x * w;
            ay += tY.y * w;
        }
        float n2 = ax * ax + ay * ay;
        float inv = (n2 > 0.0f) ? rsq_fast(n2) : 1.0f;
        ox[k] = ax * inv;
        oy[k] = ay * inv;
    }

    if (FINAL) {
        float4* px = (float4*)&dstP[((size_t)(b * 2 + 0) << 20) + y * Ww + x0];
        px[0] = make_float4(ox[0], ox[1], ox[2], ox[3]);
        px[1] = make_float4(ox[4], ox[5], ox[6], ox[7]);
        float4* py = (float4*)&dstP[((size_t)(b * 2 + 1) << 20) + y * Ww + x0];
        py[0] = make_float4(oy[0], oy[1], oy[2], oy[3]);
        py[1] = make_float4(oy[4], oy[5], oy[6], oy[7]);
    } else {
        float4* dp = (float4*)&dstI[rowbase + x0];
        dp[0] = make_float4(ox[0], oy[0], ox[1], oy[1]);
        dp[1] = make_float4(ox[2], oy[2], ox[3], oy[3]);
        dp[2] = make_float4(ox[4], oy[4], ox[5], oy[5]);
        dp[3] = make_float4(ox[6], oy[6], ox[7], oy[7]);
    }
}

extern "C" void kernel_launch(void* const* d_in, const int* in_sizes, int n_in,
                              void* d_out, int out_size, void* d_ws, size_t ws_size,
                              hipStream_t stream) {
    const float* in = (const float*)d_in[0];
    float* out = (float*)d_out;
    char* ws = (char*)d_ws;

    float* magE = (float*)ws;                                           // 32 MB
    float2* tA = (float2*)(ws + (size_t)NPIX * sizeof(float));          // 64 MB
    float* partials = (float*)(ws + (size_t)NPIX * sizeof(float)
                                  + (size_t)NPIX * sizeof(float2));
    float* scalep = partials + SOBEL_BLOCKS;
    float2* tOut = (float2*)out;

    sobel_kernel<<<SOBEL_BLOCKS, TPB, 0, stream>>>(in, tOut, magE, partials);
    max_reduce_kernel<<<1, 1024, 0, stream>>>(partials, scalep);
    prep_kernel<<<NPIX / 4 / TPB, TPB, 0, stream>>>((float4*)magE, scalep);

    // iteration 1
    etf_v<<<VBLK, TPB, 0, stream>>>(tOut, tA, magE);
    etf_h<false><<<HBLK, TPB, 0, stream>>>(tA, tOut, nullptr, magE);
    // iteration 2
    etf_v<<<VBLK, TPB, 0, stream>>>(tOut, tA, magE);
    etf_h<false><<<HBLK, TPB, 0, stream>>>(tA, tOut, nullptr, magE);
    // iteration 3
    etf_v<<<VBLK, TPB, 0, stream>>>(tOut, tA, magE);
    etf_h<true ><<<HBLK, TPB, 0, stream>>>(tA, nullptr, out, magE);
}